// Round 5
// baseline (258.278 us; speedup 1.0000x reference)
//
#include <hip/hip_runtime.h>
#include <hip/hip_bf16.h>

typedef __bf16 bf16_t;
typedef __bf16 bf16x8 __attribute__((ext_vector_type(8)));
typedef float f32x4 __attribute__((ext_vector_type(4)));
typedef float f32x16 __attribute__((ext_vector_type(16)));

#define MFMA16(a, b, c) __builtin_amdgcn_mfma_f32_16x16x32_bf16((a), (b), (c), 0, 0, 0)
#define MFMA32(a, b, c) __builtin_amdgcn_mfma_f32_32x32x16_bf16((a), (b), (c), 0, 0, 0)

constexpr int BATCH = 8, CH = 256, IC = 128, NPOS = 4096;
// softmax scale: 1/(sqrt(128)*0.05) * log2(e)  — folded into kt at k_qkv epilogue
constexpr float SM_C = 2.5503488f;

// ---- workspace layout (bytes) ----
constexpr size_t OFF_XT    = 0;         // bf16 [8][4096][256] x_t; later pacc bf16 [8][2][4096][128]
constexpr size_t OFF_QT    = 16777216;  // bf16 [8][4096][128] (centered)
constexpr size_t OFF_KT    = 25165824;  // bf16 [8][4096][128] (centered, *SM_C)
constexpr size_t OFF_V     = 33554432;  // bf16 [8][128][4096]
constexpr size_t OFF_WQKV  = 41943040;  // bf16 [384][256]
constexpr size_t OFF_WOUT  = 42139648;  // bf16 [256][128]
constexpr size_t OFF_XMEAN = 42205184;  // f32 [8][256]
constexpr size_t OFF_QKM   = 42213376;  // f32 [8][256]
constexpr size_t OFF_PL    = 42221568;  // f32 [8][2][4096]

__device__ __forceinline__ void gload_lds16(const char* g, char* lds) {
    __builtin_amdgcn_global_load_lds((const __attribute__((address_space(1))) unsigned int*)g,
                                     (__attribute__((address_space(3))) unsigned int*)lds, 16, 0,
                                     0);
}
__device__ __forceinline__ float fexp2(float x) {
    float r;
    asm("v_exp_f32 %0, %1" : "=v"(r) : "v"(x));
    return r;
}
__device__ __forceinline__ int cvtpk(float lo, float hi) {
    int r;
    asm("v_cvt_pk_bf16_f32 %0, %1, %2" : "=v"(r) : "v"(lo), "v"(hi));
    return r;
}

// ---------------- small prep kernels ----------------
__global__ void k_convert_w(const float* __restrict__ wqkv, const float* __restrict__ wout,
                            bf16_t* __restrict__ wqkv_b, bf16_t* __restrict__ wout_b) {
    int idx = blockIdx.x * 256 + threadIdx.x;
    if (idx < 384 * 256) wqkv_b[idx] = (bf16_t)wqkv[idx];
    int j = idx - 384 * 256;
    if (j >= 0 && j < 256 * 128) wout_b[j] = (bf16_t)wout[j];
}

__global__ void k_xmean(const float* __restrict__ x, float* __restrict__ xmean) {
    int c = blockIdx.x, b = blockIdx.y;
    const float4* xv = (const float4*)(x + ((size_t)(b * CH + c)) * NPOS);
    float s = 0.f;
#pragma unroll
    for (int r = 0; r < 4; r++) {
        float4 v = xv[r * 256 + threadIdx.x];
        s += v.x + v.y + v.z + v.w;
    }
    __shared__ float red[256];
    red[threadIdx.x] = s;
    __syncthreads();
    for (int st = 128; st > 0; st >>= 1) {
        if (threadIdx.x < st) red[threadIdx.x] += red[threadIdx.x + st];
        __syncthreads();
    }
    if (threadIdx.x == 0) xmean[b * CH + c] = red[0] * (1.0f / NPOS);
}

// qkmean[b][o] = sum_c w_qkv[o][c] * xmean[b][c]   (bias cancels in centering)
__global__ void k_qkmean(const float* __restrict__ wqkv, const float* __restrict__ xmean,
                         float* __restrict__ qkm) {
    int o = blockIdx.x, b = blockIdx.y, lane = threadIdx.x;
    float4 w = ((const float4*)(wqkv + (size_t)o * CH))[lane];
    float4 xm = ((const float4*)(xmean + b * CH))[lane];
    float s = w.x * xm.x + w.y * xm.y + w.z * xm.z + w.w * xm.w;
#pragma unroll
    for (int m = 1; m < 64; m <<= 1) s += __shfl_xor(s, m, 64);
    if (lane == 0) qkm[b * CH + o] = s;
}

// x [b][256][4096] f32 -> x_t [b][4096][256] bf16
__global__ void k_transpose(const float* __restrict__ x, bf16_t* __restrict__ xt) {
    __shared__ float t[32][33];
    int p0 = blockIdx.x * 32, c0 = blockIdx.y * 32, b = blockIdx.z;
    int i = threadIdx.x >> 5, j = threadIdx.x & 31;
#pragma unroll
    for (int q = 0; q < 4; q++) {
        int c = c0 + q * 8 + i;
        t[q * 8 + i][j] = x[((size_t)(b * CH + c)) * NPOS + p0 + j];
    }
    __syncthreads();
#pragma unroll
    for (int q = 0; q < 4; q++) {
        int p = p0 + q * 8 + i;
        xt[((size_t)(b * NPOS + p)) * CH + c0 + j] = (bf16_t)t[j][q * 8 + i];
    }
}

// ---------------- QKV projection ----------------
__global__ __launch_bounds__(256, 2) void k_qkv(const bf16_t* __restrict__ xt,
                                                const bf16_t* __restrict__ wqkv_b,
                                                const float* __restrict__ qkm,
                                                const float* __restrict__ b_qkv,
                                                bf16_t* __restrict__ qt, bf16_t* __restrict__ kt,
                                                bf16_t* __restrict__ v) {
    int bid = blockIdx.x;
    int b = bid & 7;
    int r0 = bid >> 3;  // 0..95
    int sec = r0 % 3;
    int pt = r0 / 3;
    int p0 = pt * 128;
    int wid = threadIdx.x >> 6, lane = threadIdx.x & 63;
    int g = lane >> 4, li = lane & 15;
    int wr = wid >> 1, wc = wid & 1;
    f32x4 acc[4][4] = {};
    if (sec < 2) {
        int ob = sec * 128;
#pragma unroll 1
        for (int kk = 0; kk < 8; kk++) {
            bf16x8 af[4], bfg[4];
#pragma unroll
            for (int fa = 0; fa < 4; fa++) {
                int p = p0 + wr * 64 + fa * 16 + li;
                af[fa] = *(const bf16x8*)(xt + ((size_t)(b * NPOS + p)) * CH + kk * 32 + g * 8);
            }
#pragma unroll
            for (int fb = 0; fb < 4; fb++) {
                int o = ob + wc * 64 + fb * 16 + li;
                bfg[fb] = *(const bf16x8*)(wqkv_b + (size_t)o * CH + kk * 32 + g * 8);
            }
#pragma unroll
            for (int fa = 0; fa < 4; fa++)
#pragma unroll
                for (int fb = 0; fb < 4; fb++) acc[fa][fb] = MFMA16(af[fa], bfg[fb], acc[fa][fb]);
        }
        bf16_t* dst = (sec == 0) ? qt : kt;
        float scale = (sec == 1) ? SM_C : 1.0f;  // fold softmax scale into k
#pragma unroll
        for (int fb = 0; fb < 4; fb++) {
            int ol = wc * 64 + fb * 16 + li;
            float mean = qkm[b * CH + sec * 128 + ol];
#pragma unroll
            for (int fa = 0; fa < 4; fa++)
#pragma unroll
                for (int r = 0; r < 4; r++) {
                    int p = p0 + wr * 64 + fa * 16 + g * 4 + r;
                    dst[((size_t)(b * NPOS + p)) * IC + ol] =
                        (bf16_t)((acc[fa][fb][r] - mean) * scale);
                }
        }
    } else {
#pragma unroll 1
        for (int kk = 0; kk < 8; kk++) {
            bf16x8 af[4], bfg[4];
#pragma unroll
            for (int fa = 0; fa < 4; fa++) {
                int o = 256 + wr * 64 + fa * 16 + li;
                af[fa] = *(const bf16x8*)(wqkv_b + (size_t)o * CH + kk * 32 + g * 8);
            }
#pragma unroll
            for (int fb = 0; fb < 4; fb++) {
                int p = p0 + wc * 64 + fb * 16 + li;
                bfg[fb] = *(const bf16x8*)(xt + ((size_t)(b * NPOS + p)) * CH + kk * 32 + g * 8);
            }
#pragma unroll
            for (int fa = 0; fa < 4; fa++)
#pragma unroll
                for (int fb = 0; fb < 4; fb++) acc[fa][fb] = MFMA16(af[fa], bfg[fb], acc[fa][fb]);
        }
#pragma unroll
        for (int fa = 0; fa < 4; fa++)
#pragma unroll
            for (int r = 0; r < 4; r++) {
                int oe = wr * 64 + fa * 16 + g * 4 + r;
                float bias = b_qkv[256 + oe];
#pragma unroll
                for (int fb = 0; fb < 4; fb++) {
                    int p = p0 + wc * 64 + fb * 16 + li;
                    v[((size_t)(b * IC + oe)) * NPOS + p] = (bf16_t)(acc[fa][fb][r] + bias);
                }
            }
    }
}

// ---------------- flash attention (32x32 MFMA, in-register P, wave (i,j)-split) ----
// grid 512: b = bid&7, r = bid>>3: jh = r&1 (global j half), it = r>>1 (i-tile of 128).
// waves: jw = wid>>1 (32-j subtile of 64-j body tile), ih = wid&1 (64-i half).
// Each wave: 64 i x 32 j -> 16 LDS reads, 32 MFMA32 per body. jw-pairs reduced via LDS at end.
constexpr int TJ = 64;

__global__ __launch_bounds__(256, 2) void k_attn(const bf16_t* __restrict__ qt,
                                                 const bf16_t* __restrict__ kt,
                                                 const bf16_t* __restrict__ v,
                                                 bf16_t* __restrict__ pacc,
                                                 float* __restrict__ pl) {
    // LDS: 2 x (q 16KB + v 16KB) dbuf = 64KB (reused for end reduction) + 4KB lsum
    __shared__ __attribute__((aligned(128))) char smem[2 * 32768 + 4096];
    const int bid = blockIdx.x;
    const int b = bid & 7;
    const int r0 = bid >> 3;
    const int jh = r0 & 1;
    const int it = r0 >> 1;  // 0..31
    const int jbase = jh * 2048;
    const int wid = threadIdx.x >> 6, lane = threadIdx.x & 63;
    const int col = lane & 31, h = lane >> 5;
    const int jw = wid >> 1, ih = wid & 1;
    const int iwW = it * 128 + ih * 64;  // this wave's 64-i base
    const bf16_t* ktb = kt + (size_t)b * NPOS * IC;
    const bf16_t* qtb = qt + (size_t)b * NPOS * IC;
    const bf16_t* vb = v + (size_t)b * IC * NPOS;

    // staging lane offsets (pre-swizzled global source: chunk ^= row&7)
    int qoff_[4], voff_[4];
#pragma unroll
    for (int u = 0; u < 4; u++) {
        int t = wid * 4 + u;
        int qrow = 4 * t + (lane >> 4);  // q-tile [64][256B]: 16 chunks/row
        qoff_[u] = qrow * 256 + (((lane & 15) ^ (qrow & 7)) << 4);
        int vrow = 8 * t + (lane >> 3);  // v-tile [128][128B]: 8 chunks/row
        voff_[u] = vrow * 8192 + (((lane & 7) ^ (vrow & 7)) << 4);
    }

    auto stage = [&](int dstpar, int sj) {
        const char* qs = (const char*)qtb + (size_t)sj * 256;
        const char* vs = (const char*)vb + (size_t)sj * 2;
        char* qd = smem + dstpar * 32768;
        char* vd = qd + 16384;
#pragma unroll
        for (int u = 0; u < 4; u++) {
            gload_lds16(qs + qoff_[u], qd + (wid * 4 + u) * 1024);
            gload_lds16(vs + voff_[u], vd + (wid * 4 + u) * 1024);
        }
    };

    stage(0, jbase);  // prologue (8 loads in flight)

    // B-operand (k rows): this wave's 64 i-cols in two 32-col tiles.
    bf16x8 bk0[8], bk1[8];
#pragma unroll
    for (int ks = 0; ks < 8; ks++) {
        bk0[ks] = *(const bf16x8*)(ktb + (size_t)(iwW + col) * IC + ks * 16 + h * 8);
        bk1[ks] = *(const bf16x8*)(ktb + (size_t)(iwW + 32 + col) * IC + ks * 16 + h * 8);
    }

    f32x16 acc0[4] = {}, acc1[4] = {};  // D(PV)[c][i] for i-tile 0 / 1
    float ls0[4] = {}, ls1[4] = {};

    // exp2 + pack D(QK^T) row-block into two PV B-fragments (k-slices kl=0,1)
    auto packP = [&](const f32x16& s, float* lsx, bf16x8& o0, bf16x8& o1) {
        float e[16];
#pragma unroll
        for (int r = 0; r < 16; r++) e[r] = fexp2(s[r]);
#pragma unroll
        for (int r = 0; r < 16; r++) lsx[r & 3] += e[r];
        int w[8];
#pragma unroll
        for (int q = 0; q < 8; q++) w[q] = cvtpk(e[2 * q], e[2 * q + 1]);
        asm("v_permlane32_swap_b32 %0, %1" : "+v"(w[0]), "+v"(w[2]));
        asm("v_permlane32_swap_b32 %0, %1" : "+v"(w[1]), "+v"(w[3]));
        asm("v_permlane32_swap_b32 %0, %1" : "+v"(w[4]), "+v"(w[6]));
        asm("v_permlane32_swap_b32 %0, %1" : "+v"(w[5]), "+v"(w[7]));
        union {
            int u[4];
            bf16x8 v;
        } t0, t1;
        t0.u[0] = w[0]; t0.u[1] = w[1]; t0.u[2] = w[2]; t0.u[3] = w[3];
        t1.u[0] = w[4]; t1.u[1] = w[5]; t1.u[2] = w[6]; t1.u[3] = w[7];
        o0 = t0.v;
        o1 = t1.v;
    };

    auto body = [&](int par, int nextj) {
        stage(par ^ 1, nextj);                            // prefetch next tile (8 loads)
        asm volatile("s_waitcnt vmcnt(8)" ::: "memory");  // current tile's loads done
        __builtin_amdgcn_s_barrier();
        asm volatile("" ::: "memory");
        const char* qb = smem + par * 32768;
        const char* vbuf = qb + 16384;
        // QK^T for this wave's jw: D[j][i], A = q rows, B = bk (two i-tiles)
        f32x16 sA = {}, sB = {};
        __builtin_amdgcn_s_setprio(1);
#pragma unroll
        for (int ks = 0; ks < 8; ks++) {
            bf16x8 aq = *(const bf16x8*)(qb + (jw * 32 + col) * 256 +
                                         (((ks * 2 + h) ^ (col & 7)) << 4));
            sA = MFMA32(aq, bk0[ks], sA);
            sB = MFMA32(aq, bk1[ks], sB);
        }
        __builtin_amdgcn_s_setprio(0);
        bf16x8 pA0, pA1, pB0, pB1;
        packP(sA, ls0, pA0, pA1);
        packP(sB, ls1, pB0, pB1);
        // PV: acc[c][i] += v[c][j-slice] * P[j-slice][i]
        __builtin_amdgcn_s_setprio(1);
#pragma unroll
        for (int kl = 0; kl < 2; kl++) {
            int kg = jw * 2 + kl;
            bf16x8 pA = kl ? pA1 : pA0;
            bf16x8 pB = kl ? pB1 : pB0;
#pragma unroll
            for (int cs = 0; cs < 4; cs++) {
                bf16x8 av = *(const bf16x8*)(vbuf + (cs * 32 + col) * 128 +
                                             (((kg * 2 + h) ^ (col & 7)) << 4));
                acc0[cs] = MFMA32(av, pA, acc0[cs]);
                acc1[cs] = MFMA32(av, pB, acc1[cs]);
            }
        }
        __builtin_amdgcn_s_setprio(0);
        asm volatile("" ::: "memory");
        __builtin_amdgcn_s_barrier();  // all reads of cur buffer done before restage
    };

#pragma unroll 1
    for (int jo = 0; jo < 2048; jo += 2 * TJ) {
        body(0, jbase + ((jo + TJ) & 2047));
        body(1, jbase + ((jo + 2 * TJ) & 2047));
    }

    // ---- cross-wave (jw pair) reduction through the dead staging LDS ----
    asm volatile("s_waitcnt vmcnt(0)" ::: "memory");  // drain stray prefetch into buf0
    __syncthreads();
    float* lb = (float*)(smem + 65536);
    if (jw == 1) {
        float* db = (float*)(smem + ih * 32768);
#pragma unroll
        for (int it2 = 0; it2 < 2; it2++)
#pragma unroll
            for (int cs = 0; cs < 4; cs++) {
                const f32x16 A = it2 ? acc1[cs] : acc0[cs];
#pragma unroll
                for (int q = 0; q < 4; q++) {
                    f32x4 tv = {A[4 * q], A[4 * q + 1], A[4 * q + 2], A[4 * q + 3]};
                    *(f32x4*)(db + ((it2 * 4 + cs) * 4 + q) * 256 + lane * 4) = tv;
                }
            }
        lb[(ih * 2 + 0) * 64 + lane] = (ls0[0] + ls0[1]) + (ls0[2] + ls0[3]);
        lb[(ih * 2 + 1) * 64 + lane] = (ls1[0] + ls1[1]) + (ls1[2] + ls1[3]);
    }
    __syncthreads();
    if (jw == 0) {
        const float* db = (const float*)(smem + ih * 32768);
        float lsA = (ls0[0] + ls0[1]) + (ls0[2] + ls0[3]) + lb[(ih * 2 + 0) * 64 + lane];
        float lsB = (ls1[0] + ls1[1]) + (ls1[2] + ls1[3]) + lb[(ih * 2 + 1) * 64 + lane];
        lsA += __shfl_xor(lsA, 32, 64);
        lsB += __shfl_xor(lsB, 32, 64);
        if (h == 0) {
            pl[((size_t)(b * 2 + jh)) * NPOS + iwW + col] = lsA;
            pl[((size_t)(b * 2 + jh)) * NPOS + iwW + 32 + col] = lsB;
        }
        bf16_t* po = pacc + ((size_t)(b * 2 + jh)) * NPOS * IC;
#pragma unroll
        for (int it2 = 0; it2 < 2; it2++) {
            int i = iwW + it2 * 32 + col;
#pragma unroll
            for (int cs = 0; cs < 4; cs++) {
                f32x16 A = it2 ? acc1[cs] : acc0[cs];
#pragma unroll
                for (int q = 0; q < 4; q++) {
                    f32x4 r = *(const f32x4*)(db + ((it2 * 4 + cs) * 4 + q) * 256 + lane * 4);
#pragma unroll
                    for (int e = 0; e < 4; e++) A[4 * q + e] += r[e];
                }
#pragma unroll
                for (int q = 0; q < 8; q++) {
                    int u = cvtpk(A[2 * q], A[2 * q + 1]);
                    int c0 = cs * 32 + ((q & 1) << 1) + ((q >> 1) << 3) + 4 * h;
                    *(int*)((char*)po + ((size_t)i * IC + c0) * 2) = u;
                }
            }
        }
    }
}

// ---------------- output projection + residual (+ fused partial merge) ----------------
// B-frag = (pacc0 + pacc1) * 1/(l0+l1) computed on the fly; no yt materialization.
__global__ __launch_bounds__(256, 2) void k_out(const bf16_t* __restrict__ pacc,
                                                const float* __restrict__ pl,
                                                const bf16_t* __restrict__ wout_b,
                                                const float* __restrict__ x,
                                                const float* __restrict__ b_out,
                                                float* __restrict__ out) {
    int bid = blockIdx.x;
    int b = bid & 7;
    int r0 = bid >> 3;
    int oct = r0 & 1, pt = r0 >> 1;
    int p0 = pt * 128, oc0 = oct * 128;
    int wid = threadIdx.x >> 6, lane = threadIdx.x & 63;
    int g = lane >> 4, li = lane & 15;
    int wr = wid >> 1, wc = wid & 1;
    const bf16_t* pa0 = pacc + (size_t)(b * 2 + 0) * NPOS * IC;
    const bf16_t* pa1 = pacc + (size_t)(b * 2 + 1) * NPOS * IC;
    float inv[4];
#pragma unroll
    for (int fb = 0; fb < 4; fb++) {
        int p = p0 + wc * 64 + fb * 16 + li;
        inv[fb] = 1.0f / (pl[(size_t)(b * 2 + 0) * NPOS + p] + pl[(size_t)(b * 2 + 1) * NPOS + p]);
    }
    f32x4 acc[4][4] = {};
#pragma unroll
    for (int kk = 0; kk < 4; kk++) {
        bf16x8 af[4], bfg[4];
#pragma unroll
        for (int fa = 0; fa < 4; fa++) {
            int oc = oc0 + wr * 64 + fa * 16 + li;
            af[fa] = *(const bf16x8*)(wout_b + (size_t)oc * IC + kk * 32 + g * 8);
        }
#pragma unroll
        for (int fb = 0; fb < 4; fb++) {
            int p = p0 + wc * 64 + fb * 16 + li;
            bf16x8 a0 = *(const bf16x8*)(pa0 + (size_t)p * IC + kk * 32 + g * 8);
            bf16x8 a1 = *(const bf16x8*)(pa1 + (size_t)p * IC + kk * 32 + g * 8);
#pragma unroll
            for (int e = 0; e < 8; e++)
                bfg[fb][e] = (bf16_t)(((float)a0[e] + (float)a1[e]) * inv[fb]);
        }
#pragma unroll
        for (int fa = 0; fa < 4; fa++)
#pragma unroll
            for (int fb = 0; fb < 4; fb++) acc[fa][fb] = MFMA16(af[fa], bfg[fb], acc[fa][fb]);
    }
#pragma unroll
    for (int fa = 0; fa < 4; fa++)
#pragma unroll
        for (int r = 0; r < 4; r++) {
            int oc = oc0 + wr * 64 + fa * 16 + g * 4 + r;
            float bias = b_out[oc];
#pragma unroll
            for (int fb = 0; fb < 4; fb++) {
                int p = p0 + wc * 64 + fb * 16 + li;
                size_t idx = ((size_t)(b * CH + oc)) * NPOS + p;
                out[idx] = acc[fa][fb][r] + x[idx] + bias;
            }
        }
}

extern "C" void kernel_launch(void* const* d_in, const int* in_sizes, int n_in, void* d_out,
                              int out_size, void* d_ws, size_t ws_size, hipStream_t stream) {
    const float* x = (const float*)d_in[0];
    const float* w_qkv = (const float*)d_in[1];
    const float* b_qkv = (const float*)d_in[2];
    const float* w_out = (const float*)d_in[3];
    const float* b_out = (const float*)d_in[4];
    float* out = (float*)d_out;
    char* ws = (char*)d_ws;

    bf16_t* xt = (bf16_t*)(ws + OFF_XT);
    bf16_t* pacc = (bf16_t*)(ws + OFF_XT);  // reuses x_t (dead after k_qkv), exact fit
    bf16_t* qt = (bf16_t*)(ws + OFF_QT);
    bf16_t* kt = (bf16_t*)(ws + OFF_KT);
    bf16_t* v = (bf16_t*)(ws + OFF_V);
    bf16_t* wqkv_b = (bf16_t*)(ws + OFF_WQKV);
    bf16_t* wout_b = (bf16_t*)(ws + OFF_WOUT);
    float* xmean = (float*)(ws + OFF_XMEAN);
    float* qkm = (float*)(ws + OFF_QKM);
    float* pl = (float*)(ws + OFF_PL);

    k_convert_w<<<512, 256, 0, stream>>>(w_qkv, w_out, wqkv_b, wout_b);
    k_xmean<<<dim3(256, 8), 256, 0, stream>>>(x, xmean);
    k_qkmean<<<dim3(256, 8), 64, 0, stream>>>(w_qkv, xmean, qkm);
    k_transpose<<<dim3(128, 8, 8), 256, 0, stream>>>(x, xt);
    k_qkv<<<768, 256, 0, stream>>>(xt, wqkv_b, qkm, b_qkv, qt, kt, v);
    k_attn<<<512, 256, 0, stream>>>(qt, kt, v, pacc, pl);
    k_out<<<512, 256, 0, stream>>>(pacc, pl, wout_b, x, b_out, out);
}

// Round 6
// 142.146 us; speedup vs baseline: 1.8170x; 1.8170x over previous
//
#include <hip/hip_runtime.h>
#include <hip/hip_bf16.h>

typedef __bf16 bf16_t;
typedef __bf16 bf16x8 __attribute__((ext_vector_type(8)));
typedef float f32x4 __attribute__((ext_vector_type(4)));
typedef float f32x16 __attribute__((ext_vector_type(16)));

#define MFMA16(a, b, c) __builtin_amdgcn_mfma_f32_16x16x32_bf16((a), (b), (c), 0, 0, 0)
#define MFMA32(a, b, c) __builtin_amdgcn_mfma_f32_32x32x16_bf16((a), (b), (c), 0, 0, 0)

constexpr int CH = 256, IC = 128, NPOS = 4096;
// softmax scale: 1/(sqrt(128)*0.05) * log2(e)  — folded into kt at k_qkv epilogue
constexpr float SM_C = 2.5503488f;

// ---- workspace layout (bytes) ----
constexpr size_t OFF_XT    = 0;         // bf16 [8][4096][256] x_t; later pacc bf16 [8][2][4096][128]
constexpr size_t OFF_QT    = 16777216;  // bf16 [8][4096][128] (centered)
constexpr size_t OFF_KT    = 25165824;  // bf16 [8][4096][128] (centered, *SM_C)
constexpr size_t OFF_V     = 33554432;  // bf16 [8][128][4096]
constexpr size_t OFF_WQKV  = 41943040;  // bf16 [384][256]
constexpr size_t OFF_WOUT  = 42139648;  // bf16 [256][128]
constexpr size_t OFF_XMEAN = 42205184;  // f32 [8][256]
constexpr size_t OFF_QKM   = 42213376;  // f32 [8][256]
constexpr size_t OFF_PL    = 42221568;  // f32 [8][2][4096]

__device__ __forceinline__ void gload_lds16(const char* g, char* lds) {
    __builtin_amdgcn_global_load_lds((const __attribute__((address_space(1))) unsigned int*)g,
                                     (__attribute__((address_space(3))) unsigned int*)lds, 16, 0,
                                     0);
}
__device__ __forceinline__ float fexp2(float x) {
    float r;
    asm("v_exp_f32 %0, %1" : "=v"(r) : "v"(x));
    return r;
}
__device__ __forceinline__ int cvtpk(float lo, float hi) {
    int r;
    asm("v_cvt_pk_bf16_f32 %0, %1, %2" : "=v"(r) : "v"(lo), "v"(hi));
    return r;
}

// ---------------- prep A: weight convert + x row-means ----------------
__global__ void k_prep0(const float* __restrict__ wqkv, const float* __restrict__ wout,
                        const float* __restrict__ x, bf16_t* __restrict__ wqkv_b,
                        bf16_t* __restrict__ wout_b, float* __restrict__ xmean) {
    int bid = blockIdx.x;
    if (bid < 512) {
        int idx = bid * 256 + threadIdx.x;
        if (idx < 384 * 256) wqkv_b[idx] = (bf16_t)wqkv[idx];
        int j = idx - 384 * 256;
        if (j >= 0 && j < 256 * 128) wout_b[j] = (bf16_t)wout[j];
        return;
    }
    int xbid = bid - 512;
    int c = xbid & 255, b = xbid >> 8;
    const float4* xv = (const float4*)(x + ((size_t)(b * CH + c)) * NPOS);
    float s = 0.f;
#pragma unroll
    for (int r = 0; r < 4; r++) {
        float4 v = xv[r * 256 + threadIdx.x];
        s += v.x + v.y + v.z + v.w;
    }
    __shared__ float red[256];
    red[threadIdx.x] = s;
    __syncthreads();
    for (int st = 128; st > 0; st >>= 1) {
        if (threadIdx.x < st) red[threadIdx.x] += red[threadIdx.x + st];
        __syncthreads();
    }
    if (threadIdx.x == 0) xmean[b * CH + c] = red[0] * (1.0f / NPOS);
}

// ---------------- prep B: x transpose->bf16 + qk means ----------------
// blocks 0..8191: x [b][256][4096] f32 -> x_t [b][4096][256] bf16
// blocks 8192..8703: qkm[b][o] = sum_c w_qkv[o][c] * xmean[b][c]
__global__ void k_prep1(const float* __restrict__ x, const float* __restrict__ wqkv,
                        const float* __restrict__ xmean, bf16_t* __restrict__ xt,
                        float* __restrict__ qkm) {
    int bid = blockIdx.x;
    if (bid >= 8192) {
        int xbid = bid - 8192;
        int wid = threadIdx.x >> 6, lane = threadIdx.x & 63;
        int o = (xbid & 63) * 4 + wid, b = xbid >> 6;
        float4 w = ((const float4*)(wqkv + (size_t)o * CH))[lane];
        float4 xm = ((const float4*)(xmean + b * CH))[lane];
        float s = w.x * xm.x + w.y * xm.y + w.z * xm.z + w.w * xm.w;
#pragma unroll
        for (int m = 1; m < 64; m <<= 1) s += __shfl_xor(s, m, 64);
        if (lane == 0) qkm[b * CH + o] = s;
        return;
    }
    __shared__ float t[32][33];
    int p0 = (bid & 127) * 32, c0 = ((bid >> 7) & 7) * 32, b = bid >> 10;
    int i = threadIdx.x >> 5, j = threadIdx.x & 31;
#pragma unroll
    for (int q = 0; q < 4; q++) {
        int c = c0 + q * 8 + i;
        t[q * 8 + i][j] = x[((size_t)(b * CH + c)) * NPOS + p0 + j];
    }
    __syncthreads();
#pragma unroll
    for (int q = 0; q < 4; q++) {
        int p = p0 + q * 8 + i;
        xt[((size_t)(b * NPOS + p)) * CH + c0 + j] = (bf16_t)t[j][q * 8 + i];
    }
}

// ---------------- QKV projection ----------------
__global__ __launch_bounds__(256, 2) void k_qkv(const bf16_t* __restrict__ xt,
                                                const bf16_t* __restrict__ wqkv_b,
                                                const float* __restrict__ qkm,
                                                const float* __restrict__ b_qkv,
                                                bf16_t* __restrict__ qt, bf16_t* __restrict__ kt,
                                                bf16_t* __restrict__ v) {
    int bid = blockIdx.x;
    int b = bid & 7;
    int r0 = bid >> 3;  // 0..95
    int sec = r0 % 3;
    int pt = r0 / 3;
    int p0 = pt * 128;
    int wid = threadIdx.x >> 6, lane = threadIdx.x & 63;
    int g = lane >> 4, li = lane & 15;
    int wr = wid >> 1, wc = wid & 1;
    f32x4 acc[4][4] = {};
    if (sec < 2) {
        int ob = sec * 128;
#pragma unroll 1
        for (int kk = 0; kk < 8; kk++) {
            bf16x8 af[4], bfg[4];
#pragma unroll
            for (int fa = 0; fa < 4; fa++) {
                int p = p0 + wr * 64 + fa * 16 + li;
                af[fa] = *(const bf16x8*)(xt + ((size_t)(b * NPOS + p)) * CH + kk * 32 + g * 8);
            }
#pragma unroll
            for (int fb = 0; fb < 4; fb++) {
                int o = ob + wc * 64 + fb * 16 + li;
                bfg[fb] = *(const bf16x8*)(wqkv_b + (size_t)o * CH + kk * 32 + g * 8);
            }
#pragma unroll
            for (int fa = 0; fa < 4; fa++)
#pragma unroll
                for (int fb = 0; fb < 4; fb++) acc[fa][fb] = MFMA16(af[fa], bfg[fb], acc[fa][fb]);
        }
        bf16_t* dst = (sec == 0) ? qt : kt;
        float scale = (sec == 1) ? SM_C : 1.0f;  // fold softmax scale into k
#pragma unroll
        for (int fb = 0; fb < 4; fb++) {
            int ol = wc * 64 + fb * 16 + li;
            float mean = qkm[b * CH + sec * 128 + ol];
#pragma unroll
            for (int fa = 0; fa < 4; fa++)
#pragma unroll
                for (int r = 0; r < 4; r++) {
                    int p = p0 + wr * 64 + fa * 16 + g * 4 + r;
                    dst[((size_t)(b * NPOS + p)) * IC + ol] =
                        (bf16_t)((acc[fa][fb][r] - mean) * scale);
                }
        }
    } else {
#pragma unroll 1
        for (int kk = 0; kk < 8; kk++) {
            bf16x8 af[4], bfg[4];
#pragma unroll
            for (int fa = 0; fa < 4; fa++) {
                int o = 256 + wr * 64 + fa * 16 + li;
                af[fa] = *(const bf16x8*)(wqkv_b + (size_t)o * CH + kk * 32 + g * 8);
            }
#pragma unroll
            for (int fb = 0; fb < 4; fb++) {
                int p = p0 + wc * 64 + fb * 16 + li;
                bfg[fb] = *(const bf16x8*)(xt + ((size_t)(b * NPOS + p)) * CH + kk * 32 + g * 8);
            }
#pragma unroll
            for (int fa = 0; fa < 4; fa++)
#pragma unroll
                for (int fb = 0; fb < 4; fb++) acc[fa][fb] = MFMA16(af[fa], bfg[fb], acc[fa][fb]);
        }
#pragma unroll
        for (int fa = 0; fa < 4; fa++)
#pragma unroll
            for (int r = 0; r < 4; r++) {
                int oe = wr * 64 + fa * 16 + g * 4 + r;
                float bias = b_qkv[256 + oe];
#pragma unroll
                for (int fb = 0; fb < 4; fb++) {
                    int p = p0 + wc * 64 + fb * 16 + li;
                    v[((size_t)(b * IC + oe)) * NPOS + p] = (bf16_t)(acc[fa][fb][r] + bias);
                }
            }
    }
}

// ---------------- flash attention (32x32 MFMA, in-register P) ----------------
// Round-4 structure; conflict-free 4-bit XOR swizzles on both q and v tiles.
// q-tile LDS: [64 j][256 B], chunk p holds global chunk p^(j&15).
// v-tile LDS: [64 rows][256 B], row r = {c=r | c=r+64} halves; position p holds
//   global (hi,jc) with hi*8+jc = p^(r&15).
// grid 512: b = bid&7, jh = (bid>>3)&1, it = bid>>4. 4 waves x 32 i-cols.
constexpr int TJ = 64;

__global__ __launch_bounds__(256, 2) void k_attn(const bf16_t* __restrict__ qt,
                                                 const bf16_t* __restrict__ kt,
                                                 const bf16_t* __restrict__ v,
                                                 bf16_t* __restrict__ pacc,
                                                 float* __restrict__ pl) {
    __shared__ __attribute__((aligned(128))) char smem[2 * 32768];
    const int bid = blockIdx.x;
    const int b = bid & 7;
    const int r0 = bid >> 3;
    const int jh = r0 & 1;
    const int it = r0 >> 1;  // 0..31
    const int jbase = jh * 2048;
    const int wid = threadIdx.x >> 6, lane = threadIdx.x & 63;
    const int col = lane & 31, h = lane >> 5;
    const int iw0 = it * 128 + wid * 32;
    const bf16_t* ktb = kt + (size_t)b * NPOS * IC;
    const bf16_t* qtb = qt + (size_t)b * NPOS * IC;
    const bf16_t* vb = v + (size_t)b * IC * NPOS;

    // staging lane offsets (inverse-swizzled global source, linear LDS dest)
    int qoff_[4], voff_[4];
#pragma unroll
    for (int u = 0; u < 4; u++) {
        int t = wid * 4 + u;
        int qrow = 4 * t + (lane >> 4);  // q-tile: 4 rows x 16 chunks per 1KB instr
        qoff_[u] = qrow * 256 + (((lane & 15) ^ (qrow & 15)) << 4);
        int crow = 4 * t + (lane >> 4);  // v-tile: 4 rows x 16 chunks per 1KB instr
        int src = (lane & 15) ^ (crow & 15);
        voff_[u] = (crow + (src >> 3) * 64) * 8192 + (src & 7) * 16;
    }

    auto stage = [&](int dstpar, int sj) {
        const char* qs = (const char*)qtb + (size_t)sj * 256;
        const char* vs = (const char*)vb + (size_t)sj * 2;
        char* qd = smem + dstpar * 32768;
        char* vd = qd + 16384;
#pragma unroll
        for (int u = 0; u < 4; u++) {
            gload_lds16(qs + qoff_[u], qd + (wid * 4 + u) * 1024);
            gload_lds16(vs + voff_[u], vd + (wid * 4 + u) * 1024);
        }
    };

    stage(0, jbase);  // prologue (8 loads in flight)

    // B-operand (k rows): this wave's 32 i-cols, kept in registers. k = c dim.
    bf16x8 bk[8];
#pragma unroll
    for (int ks = 0; ks < 8; ks++)
        bk[ks] = *(const bf16x8*)(ktb + (size_t)(iw0 + col) * IC + ks * 16 + h * 8);

    f32x16 acc[4] = {};  // D(PV)[c][i]: 4 c-subtiles of 32
    float ls[4] = {0.f, 0.f, 0.f, 0.f};

    auto body = [&](int par, int nextj) {
        stage(par ^ 1, nextj);                            // prefetch next tile (8 loads)
        asm volatile("s_waitcnt vmcnt(8)" ::: "memory");  // current tile's loads done
        __builtin_amdgcn_s_barrier();
        asm volatile("" ::: "memory");
        const char* qb = smem + par * 32768;
        const char* vbuf = qb + 16384;
#pragma unroll
        for (int jsub = 0; jsub < 2; jsub++) {
            // QK^T: D[j][i], A = q rows from LDS, B = bk
            f32x16 s = {};
            __builtin_amdgcn_s_setprio(1);
#pragma unroll
            for (int ks = 0; ks < 8; ks++) {
                bf16x8 aq = *(const bf16x8*)(qb + (jsub * 32 + col) * 256 +
                                             (((ks * 2 + h) ^ (col & 15)) << 4));
                s = MFMA32(aq, bk[ks], s);
            }
            __builtin_amdgcn_s_setprio(0);
            // exp2 (scale pre-folded into kt), lane-local row-sum
            float e[16];
#pragma unroll
            for (int r = 0; r < 16; r++) e[r] = fexp2(s[r]);
#pragma unroll
            for (int r = 0; r < 16; r++) ls[r & 3] += e[r];
            // pack to bf16 pairs, then lane<->lane+32 swap => PV B-fragments
            int w[8];
#pragma unroll
            for (int q = 0; q < 8; q++) w[q] = cvtpk(e[2 * q], e[2 * q + 1]);
            asm("v_permlane32_swap_b32 %0, %1" : "+v"(w[0]), "+v"(w[2]));
            asm("v_permlane32_swap_b32 %0, %1" : "+v"(w[1]), "+v"(w[3]));
            asm("v_permlane32_swap_b32 %0, %1" : "+v"(w[4]), "+v"(w[6]));
            asm("v_permlane32_swap_b32 %0, %1" : "+v"(w[5]), "+v"(w[7]));
            union {
                int u[4];
                bf16x8 v;
            } pb0, pb1;
            pb0.u[0] = w[0]; pb0.u[1] = w[1]; pb0.u[2] = w[2]; pb0.u[3] = w[3];
            pb1.u[0] = w[4]; pb1.u[1] = w[5]; pb1.u[2] = w[6]; pb1.u[3] = w[7];
            // PV: D[c][i] += v-frag * P-frag, over this jsub's 32 j (2 k-steps)
            __builtin_amdgcn_s_setprio(1);
#pragma unroll
            for (int kl = 0; kl < 2; kl++) {
                int kg = jsub * 2 + kl;  // 16-j group within 64-j tile
                bf16x8 pbf = kl == 0 ? pb0.v : pb1.v;
#pragma unroll
                for (int cs = 0; cs < 4; cs++) {
                    int crow = (cs & 1) * 32 + col;
                    int p = ((cs >> 1) * 8 + kg * 2 + h) ^ (crow & 15);
                    bf16x8 av = *(const bf16x8*)(vbuf + crow * 256 + (p << 4));
                    acc[cs] = MFMA32(av, pbf, acc[cs]);
                }
            }
            __builtin_amdgcn_s_setprio(0);
        }
        asm volatile("" ::: "memory");
        __builtin_amdgcn_s_barrier();  // all reads of cur buffer done before restage
    };

#pragma unroll 1
    for (int jo = 0; jo < 2048; jo += 2 * TJ) {
        body(0, jbase + ((jo + TJ) & 2047));
        body(1, jbase + ((jo + 2 * TJ) & 2047));
    }

    // denominator: lane-local sums + lane<->lane+32 combine
    float lsum = (ls[0] + ls[1]) + (ls[2] + ls[3]);
    lsum += __shfl_xor(lsum, 32, 64);
    const int i = iw0 + col;
    if (h == 0) pl[((size_t)(b * 2 + jh)) * NPOS + i] = lsum;

    // store partial accumulator: D[c][i] layout: c = cs*32 + (r&3)+8*(r>>2)+4h
    bf16_t* po = pacc + ((size_t)(b * 2 + jh)) * NPOS * IC;
#pragma unroll
    for (int cs = 0; cs < 4; cs++)
#pragma unroll
        for (int q = 0; q < 8; q++) {
            int u = cvtpk(acc[cs][2 * q], acc[cs][2 * q + 1]);
            int c0 = cs * 32 + ((q & 1) << 1) + ((q >> 1) << 3) + 4 * h;
            *(int*)((char*)po + ((size_t)i * IC + c0) * 2) = u;
        }
}

// ---------------- output projection + residual (+ fused partial merge) ----------------
__global__ __launch_bounds__(256, 2) void k_out(const bf16_t* __restrict__ pacc,
                                                const float* __restrict__ pl,
                                                const bf16_t* __restrict__ wout_b,
                                                const float* __restrict__ x,
                                                const float* __restrict__ b_out,
                                                float* __restrict__ out) {
    int bid = blockIdx.x;
    int b = bid & 7;
    int r0 = bid >> 3;
    int oct = r0 & 1, pt = r0 >> 1;
    int p0 = pt * 128, oc0 = oct * 128;
    int wid = threadIdx.x >> 6, lane = threadIdx.x & 63;
    int g = lane >> 4, li = lane & 15;
    int wr = wid >> 1, wc = wid & 1;
    const bf16_t* pa0 = pacc + (size_t)(b * 2 + 0) * NPOS * IC;
    const bf16_t* pa1 = pacc + (size_t)(b * 2 + 1) * NPOS * IC;
    float inv[4];
#pragma unroll
    for (int fb = 0; fb < 4; fb++) {
        int p = p0 + wc * 64 + fb * 16 + li;
        inv[fb] = 1.0f / (pl[(size_t)(b * 2 + 0) * NPOS + p] + pl[(size_t)(b * 2 + 1) * NPOS + p]);
    }
    f32x4 acc[4][4] = {};
#pragma unroll
    for (int kk = 0; kk < 4; kk++) {
        bf16x8 af[4], bfg[4];
#pragma unroll
        for (int fa = 0; fa < 4; fa++) {
            int oc = oc0 + wr * 64 + fa * 16 + li;
            af[fa] = *(const bf16x8*)(wout_b + (size_t)oc * IC + kk * 32 + g * 8);
        }
#pragma unroll
        for (int fb = 0; fb < 4; fb++) {
            int p = p0 + wc * 64 + fb * 16 + li;
            bf16x8 a0 = *(const bf16x8*)(pa0 + (size_t)p * IC + kk * 32 + g * 8);
            bf16x8 a1 = *(const bf16x8*)(pa1 + (size_t)p * IC + kk * 32 + g * 8);
#pragma unroll
            for (int e = 0; e < 8; e++)
                bfg[fb][e] = (bf16_t)(((float)a0[e] + (float)a1[e]) * inv[fb]);
        }
#pragma unroll
        for (int fa = 0; fa < 4; fa++)
#pragma unroll
            for (int fb = 0; fb < 4; fb++) acc[fa][fb] = MFMA16(af[fa], bfg[fb], acc[fa][fb]);
    }
#pragma unroll
    for (int fa = 0; fa < 4; fa++)
#pragma unroll
        for (int r = 0; r < 4; r++) {
            int oc = oc0 + wr * 64 + fa * 16 + g * 4 + r;
            float bias = b_out[oc];
#pragma unroll
            for (int fb = 0; fb < 4; fb++) {
                int p = p0 + wc * 64 + fb * 16 + li;
                size_t idx = ((size_t)(b * CH + oc)) * NPOS + p;
                out[idx] = acc[fa][fb][r] + x[idx] + bias;
            }
        }
}

extern "C" void kernel_launch(void* const* d_in, const int* in_sizes, int n_in, void* d_out,
                              int out_size, void* d_ws, size_t ws_size, hipStream_t stream) {
    const float* x = (const float*)d_in[0];
    const float* w_qkv = (const float*)d_in[1];
    const float* b_qkv = (const float*)d_in[2];
    const float* w_out = (const float*)d_in[3];
    const float* b_out = (const float*)d_in[4];
    float* out = (float*)d_out;
    char* ws = (char*)d_ws;

    bf16_t* xt = (bf16_t*)(ws + OFF_XT);
    bf16_t* pacc = (bf16_t*)(ws + OFF_XT);  // reuses x_t (dead after k_qkv), exact fit
    bf16_t* qt = (bf16_t*)(ws + OFF_QT);
    bf16_t* kt = (bf16_t*)(ws + OFF_KT);
    bf16_t* v = (bf16_t*)(ws + OFF_V);
    bf16_t* wqkv_b = (bf16_t*)(ws + OFF_WQKV);
    bf16_t* wout_b = (bf16_t*)(ws + OFF_WOUT);
    float* xmean = (float*)(ws + OFF_XMEAN);
    float* qkm = (float*)(ws + OFF_QKM);
    float* pl = (float*)(ws + OFF_PL);

    k_prep0<<<2560, 256, 0, stream>>>(w_qkv, w_out, x, wqkv_b, wout_b, xmean);
    k_prep1<<<8704, 256, 0, stream>>>(x, w_qkv, xmean, xt, qkm);
    k_qkv<<<768, 256, 0, stream>>>(xt, wqkv_b, qkm, b_qkv, qt, kt, v);
    k_attn<<<512, 256, 0, stream>>>(qt, kt, v, pacc, pl);
    k_out<<<512, 256, 0, stream>>>(pacc, pl, wout_b, x, b_out, out);
}